// Round 13
// baseline (1254.017 us; speedup 1.0000x reference)
//
#include <hip/hip_runtime.h>

typedef int v4i __attribute__((ext_vector_type(4)));

#define KDIM 2048
#define NDIM 2048

#define GLOAD16(g, l) __builtin_amdgcn_global_load_lds(                      \
    (const __attribute__((address_space(1))) void*)(g),                      \
    (__attribute__((address_space(3))) void*)(l), 16, 0, 0)

// ---------------- quant kernels ----------------

__device__ __forceinline__ int pack4q(float4 v, float s) {
  int a = __float2int_rn(v.x * s);
  int b = __float2int_rn(v.y * s);
  int c = __float2int_rn(v.z * s);
  int d = __float2int_rn(v.w * s);
  a = max(-128, min(127, a)); b = max(-128, min(127, b));
  c = max(-128, min(127, c)); d = max(-128, min(127, d));
  return (a & 0xff) | ((b & 0xff) << 8) | ((c & 0xff) << 16) | ((d & 0xff) << 24);
}

__global__ __launch_bounds__(256) void quant_rows(const float* __restrict__ x,
                                                  signed char* __restrict__ q,
                                                  float* __restrict__ rscale) {
  const int row = blockIdx.x;
  const float4* xr = (const float4*)(x + (size_t)row * KDIM);
  float4 v0 = xr[threadIdx.x];
  float4 v1 = xr[256 + threadIdx.x];
  float m = fmaxf(fmaxf(fabsf(v0.x), fabsf(v0.y)), fmaxf(fabsf(v0.z), fabsf(v0.w)));
  m = fmaxf(m, fmaxf(fmaxf(fabsf(v1.x), fabsf(v1.y)), fmaxf(fabsf(v1.z), fabsf(v1.w))));
  #pragma unroll
  for (int off = 32; off > 0; off >>= 1) m = fmaxf(m, __shfl_xor(m, off));
  __shared__ float red[4];
  if ((threadIdx.x & 63) == 0) red[threadIdx.x >> 6] = m;
  __syncthreads();
  float xmax = fmaxf(fmaxf(red[0], red[1]), fmaxf(red[2], red[3]));
  xmax = fmaxf(xmax, 1e-5f);
  const float scale = 127.0f / xmax;
  int* qr = (int*)(q + (size_t)row * KDIM);
  qr[threadIdx.x] = pack4q(v0, scale);
  qr[256 + threadIdx.x] = pack4q(v1, scale);
  if (threadIdx.x == 0) rscale[row] = xmax * (1.0f / 127.0f);
}

__global__ __launch_bounds__(256) void quant_w(const float* __restrict__ W,
                                               signed char* __restrict__ Wq) {
  const int i = blockIdx.x * 256 + threadIdx.x;
  float4 v = ((const float4*)W)[i];
  int a = (int)v.x, b = (int)v.y, c = (int)v.z, d = (int)v.w;
  ((int*)Wq)[i] = (a & 0xff) | ((b << 8) & 0xff00) | ((c << 16) & 0xff0000) | (d << 24);
}

// ---- 256x256 8-wave i8 GEMM, RING-2 / 2 BLOCKS PER CU (round-13) ----
// Round-13: only change vs R10 = ring depth 4 -> 2 (LDS 128 KB -> 64 KB), so TWO
// independent blocks co-reside per CU: 16 waves/CU = 4 waves/SIMD (all prior
// variants ran 2/SIMD). Tests the occupancy/latency-hiding hypothesis: per-block
// drain stalls get covered by the sibling block's MFMA bursts (m114 overlap;
// m132's 3->2 blocks/CU drop cost -42% on the bf16 ladder).
// Ladder: stage S(t+1) during tile t into slot U^1; vmcnt(0) before the tile
// boundary (m97-style; cross-block overlap hides the drain).
// MFMA 16x16x64, 2-phase KTILE, and the R4-verified 0-conflict swizzle
// (phys 16B slot = logical ^ ((row>>1)&3), both sides) are unchanged from R10.

#define VM0 asm volatile("s_waitcnt vmcnt(0)" ::: "memory")
#define VMNONE

#define STAGE_A(UB, T)                                                       \
  GLOAD16(sa + (T) * 64, lds + (UB) + dstw);                                 \
  GLOAD16(sa + (T) * 64 + 128 * KDIM, lds + (UB) + 8192 + dstw);
#define STAGE_B(UB, T)                                                       \
  GLOAD16(sb + (T) * 64, lds + (UB) + 16384 + dstw);                         \
  GLOAD16(sb + (T) * 64 + 128 * KDIM, lds + (UB) + 24576 + dstw);

#define MF(m, n, a) acc[m][n] = __builtin_amdgcn_mfma_i32_16x16x64_i8((a), bf[n], acc[m][n], 0, 0, 0);

// UB = byte base of consumed slot; SB = byte base of staged slot (UB^32768).
#define KTILE(UB, SB, T, DOSTAGE, VMEND)                                     \
  {                                                                          \
    /* ---- phase A: read m0-3 + all B from UB; stage A-half of S(T+1) ---- */\
    v4i a0 = *(const v4i*)(lds + (UB) + aRd);                                \
    v4i a1 = *(const v4i*)(lds + (UB) + aRd + 1024);                         \
    v4i a2 = *(const v4i*)(lds + (UB) + aRd + 2048);                         \
    v4i a3 = *(const v4i*)(lds + (UB) + aRd + 3072);                         \
    bf[0] = *(const v4i*)(lds + (UB) + bRd);                                 \
    bf[1] = *(const v4i*)(lds + (UB) + bRd + 1024);                          \
    bf[2] = *(const v4i*)(lds + (UB) + bRd + 2048);                          \
    bf[3] = *(const v4i*)(lds + (UB) + bRd + 3072);                          \
    if (DOSTAGE) { STAGE_A((SB), (T) + 1) }                                  \
    __builtin_amdgcn_sched_barrier(0);                                       \
    __builtin_amdgcn_s_barrier();                                            \
    asm volatile("s_waitcnt lgkmcnt(0)" ::: "memory");                       \
    __builtin_amdgcn_sched_barrier(0);                                       \
    __builtin_amdgcn_s_setprio(1);                                           \
    MF(0, 0, a0) MF(0, 1, a0) MF(0, 2, a0) MF(0, 3, a0)                      \
    MF(1, 0, a1) MF(1, 1, a1) MF(1, 2, a1) MF(1, 3, a1)                      \
    MF(2, 0, a2) MF(2, 1, a2) MF(2, 2, a2) MF(2, 3, a2)                      \
    MF(3, 0, a3) MF(3, 1, a3) MF(3, 2, a3) MF(3, 3, a3)                      \
    __builtin_amdgcn_s_setprio(0);                                           \
    __builtin_amdgcn_sched_barrier(0);                                       \
    __builtin_amdgcn_s_barrier();                                            \
    /* ---- phase B: read m4-7 (B reused in regs); stage B-half ---- */      \
    v4i a4 = *(const v4i*)(lds + (UB) + aRd + 4096);                         \
    v4i a5 = *(const v4i*)(lds + (UB) + aRd + 5120);                         \
    v4i a6 = *(const v4i*)(lds + (UB) + aRd + 6144);                         \
    v4i a7 = *(const v4i*)(lds + (UB) + aRd + 7168);                         \
    if (DOSTAGE) { STAGE_B((SB), (T) + 1) }                                  \
    __builtin_amdgcn_sched_barrier(0);                                       \
    __builtin_amdgcn_s_barrier();                                            \
    asm volatile("s_waitcnt lgkmcnt(0)" ::: "memory");                       \
    __builtin_amdgcn_sched_barrier(0);                                       \
    __builtin_amdgcn_s_setprio(1);                                           \
    MF(4, 0, a4) MF(4, 1, a4) MF(4, 2, a4) MF(4, 3, a4)                      \
    MF(5, 0, a5) MF(5, 1, a5) MF(5, 2, a5) MF(5, 3, a5)                      \
    MF(6, 0, a6) MF(6, 1, a6) MF(6, 2, a6) MF(6, 3, a6)                      \
    MF(7, 0, a7) MF(7, 1, a7) MF(7, 2, a7) MF(7, 3, a7)                      \
    __builtin_amdgcn_s_setprio(0);                                           \
    __builtin_amdgcn_sched_barrier(0);                                       \
    VMEND;  /* S(T+1) complete before next tile reads it */                  \
    __builtin_amdgcn_s_barrier();                                            \
  }

__global__ __launch_bounds__(512, 4) void gemm_i8(const signed char* __restrict__ A,
                                                  const signed char* __restrict__ B,
                                                  const float* __restrict__ rscale,
                                                  float* __restrict__ C) {
  __shared__ __align__(16) signed char lds[65536];  // ring-2 x 32 KB -> 2 blocks/CU
  const int bid = blockIdx.x;
  const int lid = (bid & 7) * 128 + (bid >> 3);  // bijective XCD swizzle (1024 % 8 == 0)
  const int bm = lid >> 3;                       // 128 row tiles
  const int bn = lid & 7;                        // 8 col tiles
  const int tid = threadIdx.x;
  const int wid = tid >> 6;
  const int lane = tid & 63;
  const int wr = wid >> 2, wc = wid & 3;

  // staging: thread covers row = wid*16 + (lane>>2) within each 128-row half,
  // dest slot = lane&3 (HW linear: base + lane*16).
  // source logical slot = (lane&3) ^ ((row>>1)&3) = (lane&3) ^ ((lane>>3)&3).  [R4-verified]
  const int srow = wid * 16 + (lane >> 2);
  const int scol = (((lane & 3) ^ ((lane >> 3) & 3)) << 4);
  const signed char* sa = A + (size_t)(bm * 256 + srow) * KDIM + scol;
  const signed char* sb = B + (size_t)(bn * 256 + srow) * KDIM + scol;
  const int dstw = wid << 10;  // wave-uniform LDS chunk; HW adds lane*16

  // ds_read: logical k-slot = lane>>4, row = ...+(lane&15) -> physical slot
  // = (lane>>4) ^ ((lane>>1)&3).  [R4-verified: SQ_LDS_BANK_CONFLICT = 0]
  const int rslot = (((lane >> 4) ^ ((lane >> 1) & 3)) << 4);
  const int aRd = (wr * 128 + (lane & 15)) * 64 + rslot;
  const int bRd = 16384 + (wc * 64 + (lane & 15)) * 64 + rslot;

  v4i acc[8][4] = {};
  v4i bf[4];

  // prologue: stage S(0) into slot 0; drain; barrier.
  STAGE_A(0, -1 + 1) STAGE_B(0, -1 + 1)   // tile 0
  VM0;
  __builtin_amdgcn_s_barrier();

  // 32 K-tiles, ring-2: tile t consumes slot (t&1)*32768, stages S(t+1) into the
  // other slot, drains before the boundary barrier.
  for (int ti = 0; ti < 15; ++ti) {
    const int t = ti * 2;
    KTILE(0, 32768, t + 0, 1, VM0)
    KTILE(32768, 0, t + 1, 1, VM0)
  }
  KTILE(0, 32768, 30, 1, VM0)   // stages S(31)
  KTILE(32768, 0, 31, 0, VMNONE)

  // epilogue: C/D layout col = lane&15, row = (lane>>4)*4 + reg
  const int col0 = bn * 256 + wc * 64 + (lane & 15);
  const int rbase = bm * 256 + wr * 128 + ((lane >> 4) << 2);
  #pragma unroll
  for (int m = 0; m < 8; ++m) {
    #pragma unroll
    for (int r = 0; r < 4; ++r) {
      const int row = rbase + m * 16 + r;
      const float s = rscale[row];
      float* crow = C + (size_t)row * NDIM + col0;
      #pragma unroll
      for (int n = 0; n < 4; ++n) crow[n * 16] = (float)acc[m][n][r] * s;
    }
  }
}

extern "C" void kernel_launch(void* const* d_in, const int* in_sizes, int n_in,
                              void* d_out, int out_size, void* d_ws, size_t ws_size,
                              hipStream_t stream) {
  const float* x = (const float*)d_in[0];
  const float* W = (const float*)d_in[1];
  float* out = (float*)d_out;
  const int M = in_sizes[0] / KDIM;  // 32768

  signed char* q = (signed char*)d_ws;                       // M*K   = 64 MB
  signed char* Wq = q + (size_t)M * KDIM;                    // N*K   =  4 MB
  float* rscale = (float*)(Wq + (size_t)NDIM * KDIM);        // M*4   = 128 KB

  quant_rows<<<M, 256, 0, stream>>>(x, q, rscale);
  quant_w<<<(NDIM * KDIM / 4) / 256, 256, 0, stream>>>(W, Wq);
  gemm_i8<<<(M / 256) * (NDIM / 256), 512, 0, stream>>>(q, Wq, rscale, out);
}

// Round 14
// 276.741 us; speedup vs baseline: 4.5314x; 4.5314x over previous
//
#include <hip/hip_runtime.h>

typedef int v4i __attribute__((ext_vector_type(4)));

#define KDIM 2048
#define NDIM 2048

#define GLOAD16(g, l) __builtin_amdgcn_global_load_lds(                      \
    (const __attribute__((address_space(1))) void*)(g),                      \
    (__attribute__((address_space(3))) void*)(l), 16, 0, 0)

// ---------------- quant kernels ----------------

__device__ __forceinline__ int pack4q(float4 v, float s) {
  int a = __float2int_rn(v.x * s);
  int b = __float2int_rn(v.y * s);
  int c = __float2int_rn(v.z * s);
  int d = __float2int_rn(v.w * s);
  a = max(-128, min(127, a)); b = max(-128, min(127, b));
  c = max(-128, min(127, c)); d = max(-128, min(127, d));
  return (a & 0xff) | ((b & 0xff) << 8) | ((c & 0xff) << 16) | ((d & 0xff) << 24);
}

__global__ __launch_bounds__(256) void quant_rows(const float* __restrict__ x,
                                                  signed char* __restrict__ q,
                                                  float* __restrict__ rscale) {
  const int row = blockIdx.x;
  const float4* xr = (const float4*)(x + (size_t)row * KDIM);
  float4 v0 = xr[threadIdx.x];
  float4 v1 = xr[256 + threadIdx.x];
  float m = fmaxf(fmaxf(fabsf(v0.x), fabsf(v0.y)), fmaxf(fabsf(v0.z), fabsf(v0.w)));
  m = fmaxf(m, fmaxf(fmaxf(fabsf(v1.x), fabsf(v1.y)), fmaxf(fabsf(v1.z), fabsf(v1.w))));
  #pragma unroll
  for (int off = 32; off > 0; off >>= 1) m = fmaxf(m, __shfl_xor(m, off));
  __shared__ float red[4];
  if ((threadIdx.x & 63) == 0) red[threadIdx.x >> 6] = m;
  __syncthreads();
  float xmax = fmaxf(fmaxf(red[0], red[1]), fmaxf(red[2], red[3]));
  xmax = fmaxf(xmax, 1e-5f);
  const float scale = 127.0f / xmax;
  int* qr = (int*)(q + (size_t)row * KDIM);
  qr[threadIdx.x] = pack4q(v0, scale);
  qr[256 + threadIdx.x] = pack4q(v1, scale);
  if (threadIdx.x == 0) rscale[row] = xmax * (1.0f / 127.0f);
}

__global__ __launch_bounds__(256) void quant_w(const float* __restrict__ W,
                                               signed char* __restrict__ Wq) {
  const int i = blockIdx.x * 256 + threadIdx.x;
  float4 v = ((const float4*)W)[i];
  int a = (int)v.x, b = (int)v.y, c = (int)v.z, d = (int)v.w;
  ((int*)Wq)[i] = (a & 0xff) | ((b << 8) & 0xff00) | ((c << 16) & 0xff0000) | (d << 24);
}

// ---- 128x128 4-wave i8 GEMM, ring-2, 3 BLOCKS/CU (m97-analog, round-14) ----
// Round-14: valid occupancy test (R13 spilled). Small block: 4 waves, wave-tile
// 64x64 -> acc[4][4] = 64 VGPR; launch_bounds(256,3) => 3 waves/SIMD, 3 blocks/CU
// (12 waves/CU). Blocks are INDEPENDENT barrier groups: each block's lgkm/vmcnt/
// barrier drains overlap the other blocks' MFMA bursts (m114/m97 implicit overlap
// — the mechanism absent in all 2-waves/SIMD variants, R4-R12).
// Loop (m97-simple): ds_read 8 frags from buf U -> 16 MFMA (compiler lgkm waits)
// -> stage S(t+1) into U^1 -> vmcnt(0) -> barrier -> swap.
// Swizzle (R4-verified 0-conflict): phys 16B slot = logical ^ ((row>>1)&3),
// applied on global source (gload_lds dest linear) and ds_read addrs.

#define VM0 asm volatile("s_waitcnt vmcnt(0)" ::: "memory")

// buffer U base = U*16384: A[128][64B] at +0, B[128][64B] at +8192.
// 4 gloads: each covers 64 rows (256 thr x 16 B / 64 B per row).
#define STAGE(U, T)                                                          \
  GLOAD16(sa + (T) * 64,            lds + (U) * 16384 + dstw);               \
  GLOAD16(sa + (T) * 64 + 64 * KDIM, lds + (U) * 16384 + 4096 + dstw);       \
  GLOAD16(sb + (T) * 64,            lds + (U) * 16384 + 8192 + dstw);        \
  GLOAD16(sb + (T) * 64 + 64 * KDIM, lds + (U) * 16384 + 12288 + dstw);

#define MF1(m, n, A, BF) acc[m][n] = __builtin_amdgcn_mfma_i32_16x16x64_i8((A), (BF), acc[m][n], 0, 0, 0);

#define KTILE(U, T, DOSTAGE)                                                 \
  {                                                                          \
    v4i a0 = *(const v4i*)(lds + (U) * 16384 + aRd);                         \
    v4i a1 = *(const v4i*)(lds + (U) * 16384 + aRd + 1024);                  \
    v4i a2 = *(const v4i*)(lds + (U) * 16384 + aRd + 2048);                  \
    v4i a3 = *(const v4i*)(lds + (U) * 16384 + aRd + 3072);                  \
    v4i b0 = *(const v4i*)(lds + (U) * 16384 + bRd);                         \
    v4i b1 = *(const v4i*)(lds + (U) * 16384 + bRd + 1024);                  \
    v4i b2 = *(const v4i*)(lds + (U) * 16384 + bRd + 2048);                  \
    v4i b3 = *(const v4i*)(lds + (U) * 16384 + bRd + 3072);                  \
    __builtin_amdgcn_s_setprio(1);                                           \
    MF1(0, 0, a0, b0) MF1(0, 1, a0, b1) MF1(0, 2, a0, b2) MF1(0, 3, a0, b3)  \
    MF1(1, 0, a1, b0) MF1(1, 1, a1, b1) MF1(1, 2, a1, b2) MF1(1, 3, a1, b3)  \
    MF1(2, 0, a2, b0) MF1(2, 1, a2, b1) MF1(2, 2, a2, b2) MF1(2, 3, a2, b3)  \
    MF1(3, 0, a3, b0) MF1(3, 1, a3, b1) MF1(3, 2, a3, b2) MF1(3, 3, a3, b3)  \
    __builtin_amdgcn_s_setprio(0);                                           \
    if (DOSTAGE) { STAGE((U) ^ 1, (T) + 1) }                                 \
    VM0;                                                                     \
    __builtin_amdgcn_s_barrier();                                            \
  }

__global__ __launch_bounds__(256, 3) void gemm_i8(const signed char* __restrict__ A,
                                                  const signed char* __restrict__ B,
                                                  const float* __restrict__ rscale,
                                                  float* __restrict__ C) {
  __shared__ __align__(16) signed char lds[32768];  // ring-2 x 16 KB -> 3+ blocks/CU
  const int bid = blockIdx.x;
  const int lid = (bid & 7) * 512 + (bid >> 3);  // bijective XCD swizzle (4096 % 8 == 0)
  const int bm = lid >> 4;                       // 256 row tiles (M/128)
  const int bn = lid & 15;                       // 16 col tiles (N/128)
  const int tid = threadIdx.x;
  const int wid = tid >> 6;
  const int lane = tid & 63;
  const int wr = wid >> 1, wc = wid & 1;         // wave-tile 64x64

  // staging: per gload, thread covers row = wid*16 + (lane>>2) within each
  // 64-row half; dest slot = lane&3 (HW linear: base + lane*16).
  // source logical slot = (lane&3) ^ ((row>>1)&3) = (lane&3) ^ ((lane>>3)&3).
  const int srow = wid * 16 + (lane >> 2);
  const int scol = (((lane & 3) ^ ((lane >> 3) & 3)) << 4);
  const signed char* sa = A + (size_t)(bm * 128 + srow) * KDIM + scol;
  const signed char* sb = B + (size_t)(bn * 128 + srow) * KDIM + scol;
  const int dstw = wid << 10;  // wave-uniform LDS chunk; HW adds lane*16

  // ds_read: logical k-slot = lane>>4, row = ...+(lane&15) -> physical slot
  // = (lane>>4) ^ ((lane>>1)&3).  [R4-verified: SQ_LDS_BANK_CONFLICT = 0]
  const int rslot = (((lane >> 4) ^ ((lane >> 1) & 3)) << 4);
  const int aRd = (wr * 64 + (lane & 15)) * 64 + rslot;
  const int bRd = 8192 + (wc * 64 + (lane & 15)) * 64 + rslot;

  v4i acc[4][4] = {};

  // prologue: stage S(0); drain; barrier.
  STAGE(0, 0)
  VM0;
  __builtin_amdgcn_s_barrier();

  // 32 K-tiles, ring-2.
  for (int ti = 0; ti < 15; ++ti) {
    KTILE(0, 2 * ti + 0, 1)
    KTILE(1, 2 * ti + 1, 1)
  }
  KTILE(0, 30, 1)   // stages S(31)
  KTILE(1, 31, 0)

  // epilogue: C/D layout col = lane&15, row = (lane>>4)*4 + reg
  const int col0 = bn * 128 + wc * 64 + (lane & 15);
  const int rbase = bm * 128 + wr * 64 + ((lane >> 4) << 2);
  #pragma unroll
  for (int m = 0; m < 4; ++m) {
    #pragma unroll
    for (int r = 0; r < 4; ++r) {
      const int row = rbase + m * 16 + r;
      const float s = rscale[row];
      float* crow = C + (size_t)row * NDIM + col0;
      #pragma unroll
      for (int n = 0; n < 4; ++n) crow[n * 16] = (float)acc[m][n][r] * s;
    }
  }
}

extern "C" void kernel_launch(void* const* d_in, const int* in_sizes, int n_in,
                              void* d_out, int out_size, void* d_ws, size_t ws_size,
                              hipStream_t stream) {
  const float* x = (const float*)d_in[0];
  const float* W = (const float*)d_in[1];
  float* out = (float*)d_out;
  const int M = in_sizes[0] / KDIM;  // 32768

  signed char* q = (signed char*)d_ws;                       // M*K   = 64 MB
  signed char* Wq = q + (size_t)M * KDIM;                    // N*K   =  4 MB
  float* rscale = (float*)(Wq + (size_t)NDIM * KDIM);        // M*4   = 128 KB

  quant_rows<<<M, 256, 0, stream>>>(x, q, rscale);
  quant_w<<<(NDIM * KDIM / 4) / 256, 256, 0, stream>>>(W, Wq);
  gemm_i8<<<(M / 128) * (NDIM / 128), 256, 0, stream>>>(q, Wq, rscale, out);
}

// Round 15
// 236.441 us; speedup vs baseline: 5.3037x; 1.1704x over previous
//
#include <hip/hip_runtime.h>

typedef int v4i __attribute__((ext_vector_type(4)));

#define KDIM 2048
#define NDIM 2048

#define GLOAD16(g, l) __builtin_amdgcn_global_load_lds(                      \
    (const __attribute__((address_space(1))) void*)(g),                      \
    (__attribute__((address_space(3))) void*)(l), 16, 0, 0)

// ---------------- quant kernels ----------------

__device__ __forceinline__ int pack4q(float4 v, float s) {
  int a = __float2int_rn(v.x * s);
  int b = __float2int_rn(v.y * s);
  int c = __float2int_rn(v.z * s);
  int d = __float2int_rn(v.w * s);
  a = max(-128, min(127, a)); b = max(-128, min(127, b));
  c = max(-128, min(127, c)); d = max(-128, min(127, d));
  return (a & 0xff) | ((b & 0xff) << 8) | ((c & 0xff) << 16) | ((d & 0xff) << 24);
}

__global__ __launch_bounds__(256) void quant_rows(const float* __restrict__ x,
                                                  signed char* __restrict__ q,
                                                  float* __restrict__ rscale) {
  const int row = blockIdx.x;
  const float4* xr = (const float4*)(x + (size_t)row * KDIM);
  float4 v0 = xr[threadIdx.x];
  float4 v1 = xr[256 + threadIdx.x];
  float m = fmaxf(fmaxf(fabsf(v0.x), fabsf(v0.y)), fmaxf(fabsf(v0.z), fabsf(v0.w)));
  m = fmaxf(m, fmaxf(fmaxf(fabsf(v1.x), fabsf(v1.y)), fmaxf(fabsf(v1.z), fabsf(v1.w))));
  #pragma unroll
  for (int off = 32; off > 0; off >>= 1) m = fmaxf(m, __shfl_xor(m, off));
  __shared__ float red[4];
  if ((threadIdx.x & 63) == 0) red[threadIdx.x >> 6] = m;
  __syncthreads();
  float xmax = fmaxf(fmaxf(red[0], red[1]), fmaxf(red[2], red[3]));
  xmax = fmaxf(xmax, 1e-5f);
  const float scale = 127.0f / xmax;
  int* qr = (int*)(q + (size_t)row * KDIM);
  qr[threadIdx.x] = pack4q(v0, scale);
  qr[256 + threadIdx.x] = pack4q(v1, scale);
  if (threadIdx.x == 0) rscale[row] = xmax * (1.0f / 127.0f);
}

__global__ __launch_bounds__(256) void quant_w(const float* __restrict__ W,
                                               signed char* __restrict__ Wq) {
  const int i = blockIdx.x * 256 + threadIdx.x;
  float4 v = ((const float4*)W)[i];
  int a = (int)v.x, b = (int)v.y, c = (int)v.z, d = (int)v.w;
  ((int*)Wq)[i] = (a & 0xff) | ((b << 8) & 0xff00) | ((c << 16) & 0xff0000) | (d << 24);
}

// ---- 256x256 8-wave i8 GEMM, ring-4 + counted vmcnt, 4 READ-BALANCED PHASES ----
// Round-15: only change vs R10 = each K-tile split into 4 phases with reads
// balanced at {4,3,3,2}/wave (vs R10's {8,4}) and MFMA {4,8,8,12}. Mechanism
// (from the m201 wall-match analysis): per-phase read-drain (~280-380 cyc/CU)
// must fit under the per-phase MFMA window (~160-490 cyc/SIMD) for the LDS and
// matrix pipes to overlap via intra-phase wave slip; R10's 8-read phase (750 cyc
// drain) serialized. Staging: 1 gload/phase (4/wave/tile, ring-4).
// Ladder: end-of-tile VM8 leaves S(t+2),S(t+3) in flight, waits S(t+1) exactly.
// Swizzle (R4-verified 0-conflict): phys 16B slot = logical ^ ((row>>1)&3),
// on global source (gload_lds dest linear) and ds_read addrs. MFMA 16x16x64.

#define VM8 asm volatile("s_waitcnt vmcnt(8)" ::: "memory")
#define VM4 asm volatile("s_waitcnt vmcnt(4)" ::: "memory")
#define VM0 asm volatile("s_waitcnt vmcnt(0)" ::: "memory")
#define VMNONE

#define SB __builtin_amdgcn_sched_barrier(0);
#define BAR __builtin_amdgcn_s_barrier();
#define LGKM0 asm volatile("s_waitcnt lgkmcnt(0)" ::: "memory");

#define MF(m, n, A, B) acc[m][n] = __builtin_amdgcn_mfma_i32_16x16x64_i8((A), (B), acc[m][n], 0, 0, 0);

#define KTILE(U, T, DOSTAGE, VMEND)                                          \
  {                                                                          \
    const int UB = (U) * 32768;                                              \
    const int SBB = (((U) + 3) & 3) * 32768;                                 \
    /* P0: reads a0,a1,b0,b1; stage A-half0 */                               \
    v4i a0 = *(const v4i*)(lds + UB + aRd);                                  \
    v4i a1 = *(const v4i*)(lds + UB + aRd + 1024);                           \
    v4i b0 = *(const v4i*)(lds + UB + bRd);                                  \
    v4i b1 = *(const v4i*)(lds + UB + bRd + 1024);                           \
    if (DOSTAGE) { GLOAD16(sa + ((T) + 3) * 64, lds + SBB + dstw); }         \
    SB BAR LGKM0 SB                                                          \
    __builtin_amdgcn_s_setprio(1);                                           \
    MF(0, 0, a0, b0) MF(0, 1, a0, b1) MF(1, 0, a1, b0) MF(1, 1, a1, b1)      \
    __builtin_amdgcn_s_setprio(0);                                           \
    SB BAR                                                                   \
    /* P1: reads a2,a3,b2; stage A-half1 */                                  \
    v4i a2 = *(const v4i*)(lds + UB + aRd + 2048);                           \
    v4i a3 = *(const v4i*)(lds + UB + aRd + 3072);                           \
    v4i b2 = *(const v4i*)(lds + UB + bRd + 2048);                           \
    if (DOSTAGE) { GLOAD16(sa + ((T) + 3) * 64 + 128 * KDIM, lds + SBB + 8192 + dstw); } \
    SB BAR LGKM0 SB                                                          \
    __builtin_amdgcn_s_setprio(1);                                           \
    MF(2, 0, a2, b0) MF(2, 1, a2, b1) MF(3, 0, a3, b0) MF(3, 1, a3, b1)      \
    MF(0, 2, a0, b2) MF(1, 2, a1, b2) MF(2, 2, a2, b2) MF(3, 2, a3, b2)      \
    __builtin_amdgcn_s_setprio(0);                                           \
    SB BAR                                                                   \
    /* P2: reads a4,a5,b3; stage B-half0 */                                  \
    v4i a4 = *(const v4i*)(lds + UB + aRd + 4096);                           \
    v4i a5 = *(const v4i*)(lds + UB + aRd + 5120);                           \
    v4i b3 = *(const v4i*)(lds + UB + bRd + 3072);                           \
    if (DOSTAGE) { GLOAD16(sb + ((T) + 3) * 64, lds + SBB + 16384 + dstw); } \
    SB BAR LGKM0 SB                                                          \
    __builtin_amdgcn_s_setprio(1);                                           \
    MF(0, 3, a0, b3) MF(1, 3, a1, b3) MF(2, 3, a2, b3) MF(3, 3, a3, b3)      \
    MF(4, 0, a4, b0) MF(4, 1, a4, b1) MF(5, 0, a5, b0) MF(5, 1, a5, b1)      \
    __builtin_amdgcn_s_setprio(0);                                           \
    SB BAR                                                                   \
    /* P3: reads a6,a7; stage B-half1; tile-boundary vmcnt */                \
    v4i a6 = *(const v4i*)(lds + UB + aRd + 6144);                           \
    v4i a7 = *(const v4i*)(lds + UB + aRd + 7168);                           \
    if (DOSTAGE) { GLOAD16(sb + ((T) + 3) * 64 + 128 * KDIM, lds + SBB + 24576 + dstw); } \
    SB BAR LGKM0 SB                                                          \
    __builtin_amdgcn_s_setprio(1);                                           \
    MF(4, 2, a4, b2) MF(4, 3, a4, b3) MF(5, 2, a5, b2) MF(5, 3, a5, b3)      \
    MF(6, 0, a6, b0) MF(6, 1, a6, b1) MF(6, 2, a6, b2) MF(6, 3, a6, b3)      \
    MF(7, 0, a7, b0) MF(7, 1, a7, b1) MF(7, 2, a7, b2) MF(7, 3, a7, b3)      \
    __builtin_amdgcn_s_setprio(0);                                           \
    SB                                                                       \
    VMEND;                                                                   \
    BAR                                                                      \
  }

__global__ __launch_bounds__(512, 2) void gemm_i8(const signed char* __restrict__ A,
                                                  const signed char* __restrict__ B,
                                                  const float* __restrict__ rscale,
                                                  float* __restrict__ C) {
  __shared__ __align__(16) signed char lds[131072];
  const int bid = blockIdx.x;
  const int lid = (bid & 7) * 128 + (bid >> 3);  // bijective XCD swizzle (1024 % 8 == 0)
  const int bm = lid >> 3;                       // 128 row tiles
  const int bn = lid & 7;                        // 8 col tiles
  const int tid = threadIdx.x;
  const int wid = tid >> 6;
  const int lane = tid & 63;
  const int wr = wid >> 2, wc = wid & 3;

  // staging: thread covers row = wid*16 + (lane>>2) within each 128-row half,
  // dest slot = lane&3 (HW linear: base + lane*16).
  // source logical slot = (lane&3) ^ ((row>>1)&3) = (lane&3) ^ ((lane>>3)&3).  [R4-verified]
  const int srow = wid * 16 + (lane >> 2);
  const int scol = (((lane & 3) ^ ((lane >> 3) & 3)) << 4);
  const signed char* sa = A + (size_t)(bm * 256 + srow) * KDIM + scol;
  const signed char* sb = B + (size_t)(bn * 256 + srow) * KDIM + scol;
  const int dstw = wid << 10;  // wave-uniform LDS chunk; HW adds lane*16

  // ds_read: logical k-slot = lane>>4, row = ...+(lane&15) -> physical slot
  // = (lane>>4) ^ ((lane>>1)&3).  [R4-verified: SQ_LDS_BANK_CONFLICT = 0]
  const int rslot = (((lane >> 4) ^ ((lane >> 1) & 3)) << 4);
  const int aRd = (wr * 128 + (lane & 15)) * 64 + rslot;
  const int bRd = 16384 + (wc * 64 + (lane & 15)) * 64 + rslot;

  v4i acc[8][4] = {};

  // prologue: stage S(0), S(1), S(2) (4 gloads each); VM8 => S(0) complete,
  // S(1),S(2) in flight.
  GLOAD16(sa, lds + dstw);
  GLOAD16(sa + 128 * KDIM, lds + 8192 + dstw);
  GLOAD16(sb, lds + 16384 + dstw);
  GLOAD16(sb + 128 * KDIM, lds + 24576 + dstw);
  GLOAD16(sa + 64, lds + 32768 + dstw);
  GLOAD16(sa + 64 + 128 * KDIM, lds + 32768 + 8192 + dstw);
  GLOAD16(sb + 64, lds + 32768 + 16384 + dstw);
  GLOAD16(sb + 64 + 128 * KDIM, lds + 32768 + 24576 + dstw);
  GLOAD16(sa + 128, lds + 65536 + dstw);
  GLOAD16(sa + 128 + 128 * KDIM, lds + 65536 + 8192 + dstw);
  GLOAD16(sb + 128, lds + 65536 + 16384 + dstw);
  GLOAD16(sb + 128 + 128 * KDIM, lds + 65536 + 24576 + dstw);
  VM8;
  __builtin_amdgcn_s_barrier();

  for (int ti = 0; ti < 7; ++ti) {
    const int t = ti * 4;
    KTILE(0, t + 0, 1, VM8)
    KTILE(1, t + 1, 1, VM8)
    KTILE(2, t + 2, 1, VM8)
    KTILE(3, t + 3, 1, VM8)
  }
  KTILE(0, 28, 1, VM8)    // stages S(31)
  KTILE(1, 29, 0, VM4)    // waits S(30)
  KTILE(2, 30, 0, VM0)    // waits S(31)
  KTILE(3, 31, 0, VMNONE)

  // epilogue: C/D layout col = lane&15, row = (lane>>4)*4 + reg
  const int col0 = bn * 256 + wc * 64 + (lane & 15);
  const int rbase = bm * 256 + wr * 128 + ((lane >> 4) << 2);
  #pragma unroll
  for (int m = 0; m < 8; ++m) {
    #pragma unroll
    for (int r = 0; r < 4; ++r) {
      const int row = rbase + m * 16 + r;
      const float s = rscale[row];
      float* crow = C + (size_t)row * NDIM + col0;
      #pragma unroll
      for (int n = 0; n < 4; ++n) crow[n * 16] = (float)acc[m][n][r] * s;
    }
  }
}

extern "C" void kernel_launch(void* const* d_in, const int* in_sizes, int n_in,
                              void* d_out, int out_size, void* d_ws, size_t ws_size,
                              hipStream_t stream) {
  const float* x = (const float*)d_in[0];
  const float* W = (const float*)d_in[1];
  float* out = (float*)d_out;
  const int M = in_sizes[0] / KDIM;  // 32768

  signed char* q = (signed char*)d_ws;                       // M*K   = 64 MB
  signed char* Wq = q + (size_t)M * KDIM;                    // N*K   =  4 MB
  float* rscale = (float*)(Wq + (size_t)NDIM * KDIM);        // M*4   = 128 KB

  quant_rows<<<M, 256, 0, stream>>>(x, q, rscale);
  quant_w<<<(NDIM * KDIM / 4) / 256, 256, 0, stream>>>(W, Wq);
  gemm_i8<<<(M / 256) * (NDIM / 256), 512, 0, stream>>>(q, Wq, rscale, out);
}

// Round 16
// 231.999 us; speedup vs baseline: 5.4053x; 1.0191x over previous
//
#include <hip/hip_runtime.h>

typedef int v4i __attribute__((ext_vector_type(4)));

#define KDIM 2048
#define NDIM 2048

#define GLOAD16(g, l) __builtin_amdgcn_global_load_lds(                      \
    (const __attribute__((address_space(1))) void*)(g),                      \
    (__attribute__((address_space(3))) void*)(l), 16, 0, 0)

// ---------------- quant kernels ----------------

__device__ __forceinline__ int pack4q(float4 v, float s) {
  int a = __float2int_rn(v.x * s);
  int b = __float2int_rn(v.y * s);
  int c = __float2int_rn(v.z * s);
  int d = __float2int_rn(v.w * s);
  a = max(-128, min(127, a)); b = max(-128, min(127, b));
  c = max(-128, min(127, c)); d = max(-128, min(127, d));
  return (a & 0xff) | ((b & 0xff) << 8) | ((c & 0xff) << 16) | ((d & 0xff) << 24);
}

__global__ __launch_bounds__(256) void quant_rows(const float* __restrict__ x,
                                                  signed char* __restrict__ q,
                                                  float* __restrict__ rscale) {
  const int row = blockIdx.x;
  const float4* xr = (const float4*)(x + (size_t)row * KDIM);
  float4 v0 = xr[threadIdx.x];
  float4 v1 = xr[256 + threadIdx.x];
  float m = fmaxf(fmaxf(fabsf(v0.x), fabsf(v0.y)), fmaxf(fabsf(v0.z), fabsf(v0.w)));
  m = fmaxf(m, fmaxf(fmaxf(fabsf(v1.x), fabsf(v1.y)), fmaxf(fabsf(v1.z), fabsf(v1.w))));
  #pragma unroll
  for (int off = 32; off > 0; off >>= 1) m = fmaxf(m, __shfl_xor(m, off));
  __shared__ float red[4];
  if ((threadIdx.x & 63) == 0) red[threadIdx.x >> 6] = m;
  __syncthreads();
  float xmax = fmaxf(fmaxf(red[0], red[1]), fmaxf(red[2], red[3]));
  xmax = fmaxf(xmax, 1e-5f);
  const float scale = 127.0f / xmax;
  int* qr = (int*)(q + (size_t)row * KDIM);
  qr[threadIdx.x] = pack4q(v0, scale);
  qr[256 + threadIdx.x] = pack4q(v1, scale);
  if (threadIdx.x == 0) rscale[row] = xmax * (1.0f / 127.0f);
}

__global__ __launch_bounds__(256) void quant_w(const float* __restrict__ W,
                                               signed char* __restrict__ Wq) {
  const int i = blockIdx.x * 256 + threadIdx.x;
  float4 v = ((const float4*)W)[i];
  int a = (int)v.x, b = (int)v.y, c = (int)v.z, d = (int)v.w;
  ((int*)Wq)[i] = (a & 0xff) | ((b << 8) & 0xff00) | ((c << 16) & 0xff0000) | (d << 24);
}

// ---- 256x256 8-wave i8 GEMM, ring-4, counted vmcnt, WAVE-SLIP phases (round-16) ----
// Round-16: only change vs R10 = phase-END barriers removed (4 -> 2 barriers per
// K-tile; barriers remain only at phase STARTS, paired with lgkmcnt(0)). Mechanism:
// R10's end-of-cluster barrier forced all 8 waves to reconverge after each MFMA
// cluster, locking read bursts into CU-wide lockstep (read-drain and MFMA windows
// serialize; measured wall = their sum across 9 schedule variants). Without the
// reconvergence barrier, waves whose reads complete early slip ahead into the next
// phase's reads while slower waves still occupy the MFMA pipe -> cross-wave overlap.
// Safety: max inter-wave slip = 1 phase; ring-4 + VM8 ladder means a slot's
// overwrite happens 6 barriers after its last read.
// Swizzle (R4-verified 0-conflict): phys 16B slot = logical ^ ((row>>1)&3), applied
// on global source (gload_lds dest linear) and ds_read addrs. MFMA 16x16x64.

#define VM8 asm volatile("s_waitcnt vmcnt(8)" ::: "memory")
#define VM4 asm volatile("s_waitcnt vmcnt(4)" ::: "memory")
#define VM0 asm volatile("s_waitcnt vmcnt(0)" ::: "memory")
#define VMNONE

#define STAGE_A(U, T)                                                        \
  GLOAD16(sa + (T) * 64, lds + (U) * 32768 + dstw);                          \
  GLOAD16(sa + (T) * 64 + 128 * KDIM, lds + (U) * 32768 + 8192 + dstw);
#define STAGE_B(U, T)                                                        \
  GLOAD16(sb + (T) * 64, lds + (U) * 32768 + 16384 + dstw);                  \
  GLOAD16(sb + (T) * 64 + 128 * KDIM, lds + (U) * 32768 + 24576 + dstw);

#define MF(m, n, a) acc[m][n] = __builtin_amdgcn_mfma_i32_16x16x64_i8((a), bf[n], acc[m][n], 0, 0, 0);

#define KTILE(U, T, DOSTAGE, VMEND)                                          \
  {                                                                          \
    /* ---- phase A: read m0-3 + all B, stage A-halves of S(T+3) ---- */     \
    v4i a0 = *(const v4i*)(lds + (U) * 32768 + aRd);                         \
    v4i a1 = *(const v4i*)(lds + (U) * 32768 + aRd + 1024);                  \
    v4i a2 = *(const v4i*)(lds + (U) * 32768 + aRd + 2048);                  \
    v4i a3 = *(const v4i*)(lds + (U) * 32768 + aRd + 3072);                  \
    bf[0] = *(const v4i*)(lds + (U) * 32768 + bRd);                          \
    bf[1] = *(const v4i*)(lds + (U) * 32768 + bRd + 1024);                   \
    bf[2] = *(const v4i*)(lds + (U) * 32768 + bRd + 2048);                   \
    bf[3] = *(const v4i*)(lds + (U) * 32768 + bRd + 3072);                   \
    if (DOSTAGE) { STAGE_A((((U) + 3) & 3), (T) + 3) }                       \
    __builtin_amdgcn_sched_barrier(0);                                       \
    asm volatile("s_waitcnt lgkmcnt(0)" ::: "memory");                       \
    __builtin_amdgcn_sched_barrier(0);                                       \
    __builtin_amdgcn_s_setprio(1);                                           \
    MF(0, 0, a0) MF(0, 1, a0) MF(0, 2, a0) MF(0, 3, a0)                      \
    MF(1, 0, a1) MF(1, 1, a1) MF(1, 2, a1) MF(1, 3, a1)                      \
    MF(2, 0, a2) MF(2, 1, a2) MF(2, 2, a2) MF(2, 3, a2)                      \
    MF(3, 0, a3) MF(3, 1, a3) MF(3, 2, a3) MF(3, 3, a3)                      \
    __builtin_amdgcn_s_setprio(0);                                           \
    /* no reconvergence barrier here: waves slip into phase B */             \
    /* ---- phase B: read m4-7 (B reused in regs), stage B-halves ---- */    \
    v4i a4 = *(const v4i*)(lds + (U) * 32768 + aRd + 4096);                  \
    v4i a5 = *(const v4i*)(lds + (U) * 32768 + aRd + 5120);                  \
    v4i a6 = *(const v4i*)(lds + (U) * 32768 + aRd + 6144);                  \
    v4i a7 = *(const v4i*)(lds + (U) * 32768 + aRd + 7168);                  \
    if (DOSTAGE) { STAGE_B((((U) + 3) & 3), (T) + 3) }                       \
    __builtin_amdgcn_sched_barrier(0);                                       \
    asm volatile("s_waitcnt lgkmcnt(0)" ::: "memory");                       \
    __builtin_amdgcn_sched_barrier(0);                                       \
    __builtin_amdgcn_s_setprio(1);                                           \
    MF(4, 0, a4) MF(4, 1, a4) MF(4, 2, a4) MF(4, 3, a4)                      \
    MF(5, 0, a5) MF(5, 1, a5) MF(5, 2, a5) MF(5, 3, a5)                      \
    MF(6, 0, a6) MF(6, 1, a6) MF(6, 2, a6) MF(6, 3, a6)                      \
    MF(7, 0, a7) MF(7, 1, a7) MF(7, 2, a7) MF(7, 3, a7)                      \
    __builtin_amdgcn_s_setprio(0);                                           \
    __builtin_amdgcn_sched_barrier(0);                                       \
    VMEND;                                                                   \
    __builtin_amdgcn_s_barrier();  /* single tile-boundary reconvergence */  \
  }

__global__ __launch_bounds__(512, 2) void gemm_i8(const signed char* __restrict__ A,
                                                  const signed char* __restrict__ B,
                                                  const float* __restrict__ rscale,
                                                  float* __restrict__ C) {
  __shared__ __align__(16) signed char lds[131072];
  const int bid = blockIdx.x;
  const int lid = (bid & 7) * 128 + (bid >> 3);  // bijective XCD swizzle (1024 % 8 == 0)
  const int bm = lid >> 3;                       // 128 row tiles
  const int bn = lid & 7;                        // 8 col tiles
  const int tid = threadIdx.x;
  const int wid = tid >> 6;
  const int lane = tid & 63;
  const int wr = wid >> 2, wc = wid & 3;

  // staging: thread covers row = wid*16 + (lane>>2) within each 128-row half,
  // dest slot = lane&3 (HW linear: base + lane*16).
  // source logical slot = (lane&3) ^ ((row>>1)&3) = (lane&3) ^ ((lane>>3)&3).  [R4-verified]
  const int srow = wid * 16 + (lane >> 2);
  const int scol = (((lane & 3) ^ ((lane >> 3) & 3)) << 4);
  const signed char* sa = A + (size_t)(bm * 256 + srow) * KDIM + scol;
  const signed char* sb = B + (size_t)(bn * 256 + srow) * KDIM + scol;
  const int dstw = wid << 10;  // wave-uniform LDS chunk; HW adds lane*16

  // ds_read: logical k-slot = lane>>4, row = ...+(lane&15) -> physical slot
  // = (lane>>4) ^ ((lane>>1)&3).  [R4-verified: SQ_LDS_BANK_CONFLICT = 0]
  const int rslot = (((lane >> 4) ^ ((lane >> 1) & 3)) << 4);
  const int aRd = (wr * 128 + (lane & 15)) * 64 + rslot;
  const int bRd = 16384 + (wc * 64 + (lane & 15)) * 64 + rslot;

  v4i acc[8][4] = {};
  v4i bf[4];

  // prologue: stage S(0), S(1), S(2); W(0)
  STAGE_A(0, 0) STAGE_B(0, 0)
  STAGE_A(1, 1) STAGE_B(1, 1)
  STAGE_A(2, 2) STAGE_B(2, 2)
  VM8;
  __builtin_amdgcn_s_barrier();

  for (int ti = 0; ti < 7; ++ti) {
    const int t = ti * 4;
    KTILE(0, t + 0, 1, VM8)
    KTILE(1, t + 1, 1, VM8)
    KTILE(2, t + 2, 1, VM8)
    KTILE(3, t + 3, 1, VM8)
  }
  KTILE(0, 28, 1, VM8)    // stages S(31)
  KTILE(1, 29, 0, VM4)    // W(30)
  KTILE(2, 30, 0, VM0)    // W(31)
  KTILE(3, 31, 0, VMNONE)

  // epilogue: C/D layout col = lane&15, row = (lane>>4)*4 + reg
  const int col0 = bn * 256 + wc * 64 + (lane & 15);
  const int rbase = bm * 256 + wr * 128 + ((lane >> 4) << 2);
  #pragma unroll
  for (int m = 0; m < 8; ++m) {
    #pragma unroll
    for (int r = 0; r < 4; ++r) {
      const int row = rbase + m * 16 + r;
      const float s = rscale[row];
      float* crow = C + (size_t)row * NDIM + col0;
      #pragma unroll
      for (int n = 0; n < 4; ++n) crow[n * 16] = (float)acc[m][n][r] * s;
    }
  }
}

extern "C" void kernel_launch(void* const* d_in, const int* in_sizes, int n_in,
                              void* d_out, int out_size, void* d_ws, size_t ws_size,
                              hipStream_t stream) {
  const float* x = (const float*)d_in[0];
  const float* W = (const float*)d_in[1];
  float* out = (float*)d_out;
  const int M = in_sizes[0] / KDIM;  // 32768

  signed char* q = (signed char*)d_ws;                       // M*K   = 64 MB
  signed char* Wq = q + (size_t)M * KDIM;                    // N*K   =  4 MB
  float* rscale = (float*)(Wq + (size_t)NDIM * KDIM);        // M*4   = 128 KB

  quant_rows<<<M, 256, 0, stream>>>(x, q, rscale);
  quant_w<<<(NDIM * KDIM / 4) / 256, 256, 0, stream>>>(W, Wq);
  gemm_i8<<<(M / 256) * (NDIM / 256), 512, 0, stream>>>(q, Wq, rscale, out);
}